// Round 11
// baseline (566.152 us; speedup 1.0000x reference)
//
#include <hip/hip_runtime.h>

typedef unsigned short u16;
typedef float floatx2 __attribute__((ext_vector_type(2)));
typedef float floatx4 __attribute__((ext_vector_type(4)));
typedef short shortx8 __attribute__((ext_vector_type(8)));

#define DIN 2048

__device__ __forceinline__ u16 f2bf(float f){
  unsigned u = __float_as_uint(f);
  u = (u + 0x7fffu + ((u>>16)&1u))>>16;
  return (u16)u;
}
__device__ __forceinline__ float sigf(float x){ return 1.f/(1.f+__expf(-x)); }
__device__ __forceinline__ float siluf(float x){ return x*sigf(x); }
__device__ __forceinline__ floatx2 max2(floatx2 a, floatx2 b){
  floatx2 r; r.x = fmaxf(a.x, b.x); r.y = fmaxf(a.y, b.y); return r;
}

// ---------------- workspace layout (bytes) ----------------
#define OFF_WINP  0ull            // 4096x1024 bf16
#define OFF_WG1   8388608ull      // 1024x2048 bf16
#define OFF_WG2   12582912ull     // 2048x1024 bf16
#define OFF_WOP   16777216ull     // 1024x2048 bf16
#define OFF_XB    20971520ull     // 1024x1024 bf16
#define OFF_XIN   23068672ull     // 1024x2048 f32 (xin -> t1acc0)
#define OFF_SGATE 31457280ull     // 1024x2048 f32 silu(gate)
#define OFF_X1    39845888ull     // 512x2048 f32  (x1 -> t1acc1)
#define OFF_X2    44040192ull     // 256x2048 f32
#define OFF_XC0   46137344ull     // ctxb bf16 (first 4MB); +4MB -> ypa1
#define OFF_XC1   54525952ull     // t1b bf16
#define OFF_FUSED 60817408ull     // 1024x2048 f32 fused
#define OFF_G3O   69206016ull     // g3o bf16 4MB
#define OFF_Y0    75497472ull     // 1024x2048 f32
#define OFF_Y1    83886080ull     // 512x2048 f32  (-> ypa0)
#define OFF_Y2    88080384ull     // 256x2048 f32
#define OFF_P0    90177536ull     // 1024x32 f32
#define OFF_P1    90308608ull     // 512x32 f32
#define OFF_P2    90374144ull     // 256x32 f32
#define OFF_HC    92274688ull     // 112 x 32768 f32 = 14,680,064 B  (chunk-local H)
#define OFF_HINIT 121634816ull    // 112 x 32768 f32 = 14,680,064 B
#define OFF_SARR  136314880ull    // 112 x 2048 f32  = 917,504 B (end 137232384)
#define OFF_BAR   137232384ull    // 4 x u32 barrier counters
// aliases
#define OFF_CTXB  OFF_XC0
#define OFF_T1B   OFF_XC1
#define OFF_T1A0  OFF_XIN
#define OFF_T1A1  OFF_X1
#define OFF_YPA0  OFF_Y1
#define OFF_YPA1  (OFF_XC0 + 4194304ull)

__device__ __forceinline__ void gld_lds16(const void* g, void* l){
  __builtin_amdgcn_global_load_lds((const __attribute__((address_space(1))) unsigned*)g,
                                   (__attribute__((address_space(3))) unsigned*)l, 16, 0, 0);
}

// manual grid barrier, hardened (R9 post-mortem):
//  - arrivals + polls at SYSTEM scope (sc0+sc1: bypass L1 AND non-coherent XCD L2 —
//    polls can never read stale; plain loads to one line don't serialize like RMWs)
//  - bar initialized by SYSTEM-scope atomic stores (no dirty-L2 writeback clobber)
//  - bounded spin (~50 ms cap): worst case = wrong answer, never a hung container.
// Data visibility (plain stores + __threadfence release/acquire) is HW-proven: R8
// passed correctness with this exact data path; only the poll was pathological.
// All 896 blocks co-resident by __launch_bounds__(256,4): 4/CU x 256 CU = 1024 >= 896.
__device__ __forceinline__ void gbar(unsigned* cnt, unsigned expected){
  __syncthreads();
  if (threadIdx.x == 0){
    __threadfence();   // release my writes to device coherence point
    __hip_atomic_fetch_add(cnt, 1u, __ATOMIC_RELAXED, __HIP_MEMORY_SCOPE_SYSTEM);
    int guard = 0;
    while (__hip_atomic_load(cnt, __ATOMIC_RELAXED, __HIP_MEMORY_SCOPE_SYSTEM) < expected
           && ++guard < 30000)
      __builtin_amdgcn_s_sleep(64);
    __threadfence();   // acquire: discard stale cached lines
  }
  __syncthreads();
}

// ---------------- f32 -> bf16 conversion (inpw + x) + barrier-counter zeroing ------
__global__ __launch_bounds__(256) void cvt_kernel(
    const float* __restrict__ s0, u16* __restrict__ d0,
    const float* __restrict__ s1, u16* __restrict__ d1,
    unsigned* __restrict__ bar)
{
  if (blockIdx.x == 0 && threadIdx.x < 4)
    __hip_atomic_store(&bar[threadIdx.x], 0u, __ATOMIC_RELAXED, __HIP_MEMORY_SCOPE_SYSTEM);
  int i = (blockIdx.x*256 + threadIdx.x)*4;
  const float* s; u16* d;
  if (i < 4194304){ s=s0; d=d0; }
  else            { s=s1; d=d1; i -= 4194304; }
  const float4 v = *(const float4*)(s + i);
  ushort4 o; o.x = f2bf(v.x); o.y = f2bf(v.y); o.z = f2bf(v.z); o.w = f2bf(v.w);
  *(ushort4*)(d + i) = o;
}

// ---------------- MFMA bt-GEMM (R1/R3-proven): BK=32, dbuf ----------
// MODE 0: G1 epilogue (xin + downsamples | silu->sgate)
// MODE 2: G3 epilogue (sigmoid * fused * sgate -> bf16)
// MODE 4: plain f32 (split-K aware via blockIdx.z)
template<int MODE, int BM>
__global__ __launch_bounds__(256) void gemm_bt(
    const u16* __restrict__ A, const u16* __restrict__ B,
    int N, int K, int Ks,
    float* __restrict__ out_f, float* __restrict__ out_f2, u16* __restrict__ out_b,
    const float* __restrict__ ex0f, const float* __restrict__ ex1f,
    float* __restrict__ ex0, float* __restrict__ ex1)
{
  constexpr int NI = BM/32;
  constexpr int IP = BM/64;
  __shared__ u16 smA[2][BM*32];
  __shared__ u16 smB[2][BM*32];
  const int tid  = threadIdx.x;
  const int m0   = blockIdx.y * BM;
  const int n0   = blockIdx.x * BM;
  const int wv   = tid >> 6;
  const int lane = tid & 63;
  const int mw   = (wv >> 1) * (BM/2);
  const int nw   = (wv & 1) * (BM/2);
  const int quad = lane >> 4;
  const int l16  = lane & 15;
  const int srow = tid >> 2;
  const int scol = (tid & 3) * 8;

  floatx4 acc[NI][NI];
#pragma unroll
  for (int i=0;i<NI;i++)
#pragma unroll
    for (int j=0;j<NI;j++) acc[i][j] = (floatx4)0.f;

  const int kStart = blockIdx.z * Ks;
  const int kEnd   = kStart + Ks;

  auto stage = [&](int buf, int k0){
#pragma unroll
    for (int p=0;p<IP;p++){
      gld_lds16(A + (size_t)(m0 + p*64 + srow)*K + k0 + scol, &smA[buf][p*2048 + wv*512]);
      gld_lds16(B + (size_t)(n0 + p*64 + srow)*K + k0 + scol, &smB[buf][p*2048 + wv*512]);
    }
  };

  stage(0, kStart);
  int cur = 0;
  for (int k0 = kStart; k0 < kEnd; k0 += 32) {
    __syncthreads();
    if (k0 + 32 < kEnd) stage(cur^1, k0+32);
    shortx8 af[NI], bfr[NI];
#pragma unroll
    for (int i=0;i<NI;i++){
      af[i]  = *(const shortx8*)&smA[cur][(mw + i*16 + l16)*32 + quad*8];
      bfr[i] = *(const shortx8*)&smB[cur][(nw + i*16 + l16)*32 + quad*8];
    }
#pragma unroll
    for (int i=0;i<NI;i++)
#pragma unroll
      for (int j=0;j<NI;j++)
        acc[i][j] = __builtin_amdgcn_mfma_f32_16x16x32_bf16(af[i], bfr[j], acc[i][j], 0, 0, 0);
    cur ^= 1;
  }

#pragma unroll
  for (int i=0;i<NI;i++){
    const int mb = m0 + mw + i*16 + quad*4;
#pragma unroll
    for (int j=0;j<NI;j++){
      const int n = n0 + nw + j*16 + l16;
      const floatx4 v4 = acc[i][j];
      if (MODE == 0){
        if (n < 2048){
#pragma unroll
          for (int r=0;r<4;r++) out_f[(size_t)(mb+r)*2048 + n] = v4[r];
          ex0[(size_t)(mb>>1)*2048 + n]       = 0.5f*(v4[0]+v4[1]);
          ex0[(size_t)((mb>>1)+1)*2048 + n]   = 0.5f*(v4[2]+v4[3]);
          ex1[(size_t)(mb>>2)*2048 + n]       = 0.25f*(v4[0]+v4[1]+v4[2]+v4[3]);
        } else {
#pragma unroll
          for (int r=0;r<4;r++) out_f2[(size_t)(mb+r)*2048 + (n-2048)] = siluf(v4[r]);
        }
      } else if (MODE == 2){
#pragma unroll
        for (int r=0;r<4;r++){
          const size_t idx = (size_t)(mb+r)*N + n;
          out_b[idx] = f2bf(sigf(v4[r]) * ex0f[idx] * ex1f[idx]);
        }
      } else {
        float* dst = blockIdx.z ? out_f2 : out_f;
#pragma unroll
        for (int r=0;r<4;r++) dst[(size_t)(mb+r)*N + n] = v4[r];
      }
    }
  }
}

// ---------------- G2 combine: t1 = silu(acc0+acc1) -> bf16 ----------------
__global__ __launch_bounds__(256) void g2_epi(const float* __restrict__ a,
    const float* __restrict__ b, u16* __restrict__ o){
  const int i = (blockIdx.x*256 + threadIdx.x)*4;
  const float4 va = *(const float4*)(a+i);
  const float4 vb = *(const float4*)(b+i);
  ushort4 r;
  r.x = f2bf(siluf(va.x+vb.x)); r.y = f2bf(siluf(va.y+vb.y));
  r.z = f2bf(siluf(va.z+vb.z)); r.w = f2bf(siluf(va.w+vb.w));
  *(ushort4*)(o+i) = r;
}

// ---------------- xproj with inline conv + piggybacked gate-weight cvt ----------
// blocks [0,1792): xproj.  blocks [1792, 7936): stream-convert gw1/gw2/opw -> bf16.
__global__ __launch_bounds__(256) void xproj_kernel(const float* __restrict__ x0,
    const float* __restrict__ x1, const float* __restrict__ x2,
    const float* __restrict__ cw, const float* __restrict__ cb,
    const float* __restrict__ xw,
    float* __restrict__ p0, float* __restrict__ p1, float* __restrict__ p2,
    const float* __restrict__ gw1c, u16* __restrict__ wG1o,
    const float* __restrict__ gw2c, u16* __restrict__ wG2o,
    const float* __restrict__ opwc, u16* __restrict__ wOpo){
  __shared__ float srow[DIN];
  if (blockIdx.x >= 1792){
    int i = (int)(blockIdx.x - 1792)*1024 + threadIdx.x*4;
    const float* sp; u16* dp;
    if (i < 2097152)      { sp=gw1c; dp=wG1o; }
    else if (i < 4194304) { sp=gw2c; dp=wG2o; i-=2097152; }
    else                  { sp=opwc; dp=wOpo; i-=4194304; }
    const float4 v = *(const float4*)(sp + i);
    ushort4 o; o.x = f2bf(v.x); o.y = f2bf(v.y); o.z = f2bf(v.z); o.w = f2bf(v.w);
    *(ushort4*)(dp + i) = o;
    return;
  }
  const int b = blockIdx.x;
  const float* xs; float* proj; int s, t;
  if (b < 1024)      { s=0; t=b;       xs=x0; proj=p0; }
  else if (b < 1536) { s=1; t=b-1024;  xs=x1; proj=p1; }
  else               { s=2; t=b-1536;  xs=x2; proj=p2; }
  const int tid = threadIdx.x;
#pragma unroll
  for (int q=0;q<2;q++){
    const int k = (q*256 + tid)*4;
    float4 xv[4];
#pragma unroll
    for (int j=0;j<4;j++){
      const int tt = t - 3 + j;
      if (tt >= 0) xv[j] = *(const float4*)(xs + (size_t)tt*DIN + k);
      else { xv[j].x = 0.f; xv[j].y = 0.f; xv[j].z = 0.f; xv[j].w = 0.f; }
    }
    const float4 w0 = *(const float4*)(cw + ((size_t)(s*DIN) + k + 0)*4);
    const float4 w1 = *(const float4*)(cw + ((size_t)(s*DIN) + k + 1)*4);
    const float4 w2 = *(const float4*)(cw + ((size_t)(s*DIN) + k + 2)*4);
    const float4 w3 = *(const float4*)(cw + ((size_t)(s*DIN) + k + 3)*4);
    const float4 cb4 = *(const float4*)(cb + (size_t)(s*DIN) + k);
    float4 r;
    r.x = siluf(cb4.x + w0.x*xv[0].x + w0.y*xv[1].x + w0.z*xv[2].x + w0.w*xv[3].x);
    r.y = siluf(cb4.y + w1.x*xv[0].y + w1.y*xv[1].y + w1.z*xv[2].y + w1.w*xv[3].y);
    r.z = siluf(cb4.z + w2.x*xv[0].z + w2.y*xv[1].z + w2.z*xv[2].z + w2.w*xv[3].z);
    r.w = siluf(cb4.w + w3.x*xv[0].w + w3.y*xv[1].w + w3.z*xv[2].w + w3.w*xv[3].w);
    *(float4*)&srow[k] = r;
  }
  __syncthreads();
  const int i = tid >> 3;
  const int j = tid & 7;
  const float4* w4 = (const float4*)(xw + ((size_t)s*32 + i)*DIN);
  const float4* s4 = (const float4*)srow;
  float acc = 0.f;
#pragma unroll 8
  for (int c=0;c<64;c++){
    const float4 sv = s4[j + 8*c];
    const float4 wv = w4[j + 8*c];
    acc += sv.x*wv.x + sv.y*wv.y + sv.z*wv.z + sv.w*wv.w;
  }
  acc += __shfl_xor(acc,1); acc += __shfl_xor(acc,2); acc += __shfl_xor(acc,4);
  if (j == 0) proj[t*32 + i] = acc;
}

// ---------------- upsample helper ----------------
__device__ __forceinline__ float ups_read(const float* __restrict__ ys, int Tin, int t, int d){
  const float scale = (float)Tin * (1.f/1024.f);
  float pos = ((float)t + 0.5f)*scale - 0.5f;
  pos = fminf(fmaxf(pos, 0.f), (float)(Tin-1));
  const int lo = (int)floorf(pos);
  const float w = pos - (float)lo;
  const int hi = min(lo+1, Tin-1);
  return ys[(size_t)lo*DIN + d]*(1.f-w) + ys[(size_t)hi*DIN + d]*w;
}

// ---------------- fused scan: p1 + combine + p2 + fuse, hardened grid barriers ----
__global__ __launch_bounds__(256, 4) void scan_fused(
    const float* __restrict__ x0, const float* __restrict__ x1, const float* __restrict__ x2,
    const float* __restrict__ p0, const float* __restrict__ p1, const float* __restrict__ p2,
    const float* __restrict__ cw, const float* __restrict__ cb,
    const float* __restrict__ dtw, const float* __restrict__ dtb,
    const float* __restrict__ Dp_all, const float* __restrict__ sw,
    float* __restrict__ Sarr, float* __restrict__ Hc, float* __restrict__ Hinit,
    float* __restrict__ y0, float* __restrict__ y1, float* __restrict__ y2,
    u16* __restrict__ ctxb, float* __restrict__ fusedo, unsigned* bar)
{
  __shared__ float sproj[16*32];
  int b = blockIdx.x;
  const float *xs, *proj; float* y; int base, s;
  if (b < 512)      { xs=x0; proj=p0; y=y0; base=0;  s=0; }
  else if (b < 768) { b-=512; xs=x1; proj=p1; y=y1; base=64; s=1; }
  else              { b-=768; xs=x2; proj=p2; y=y2; base=96; s=2; }
  const int chunk = b >> 3;
  const int tid   = threadIdx.x;
  const int d     = (b & 7)*256 + tid;
  const int t0    = chunk*16;
  {
    const int k = tid*2;
    *(float2*)&sproj[k] = *(const float2*)&proj[t0*32 + k];
  }
  __syncthreads();

  const float4 wc  = *(const float4*)(cw + ((size_t)(s*DIN) + d)*4);
  const float  cbv = cb[s*DIN + d];
  floatx2 w2[8];
  const floatx2* wr = (const floatx2*)(dtw + ((size_t)(s*DIN) + d)*16);
#pragma unroll
  for (int k=0;k<8;k++) w2[k] = wr[k];
  const float bias = dtb[s*DIN + d];
  const floatx2 eps2 = {1e-38f, 1e-38f};

  floatx2 H2[8];
#pragma unroll
  for (int k=0;k<8;k++) H2[k] = (floatx2)0.f;
  float S = 0.f;
  float dt_s[16], xcv_s[16];
  const float* xp = xs + d;
  float h0=0.f, h1=0.f, h2=0.f;
  if (chunk){
    h0 = xp[(size_t)(t0-3)*DIN];
    h1 = xp[(size_t)(t0-2)*DIN];
    h2 = xp[(size_t)(t0-1)*DIN];
  }
#pragma unroll
  for (int tt=0; tt<16; tt++){
    const float xv  = xp[(size_t)(t0+tt)*DIN];
    const float xcv = siluf(cbv + wc.x*h0 + wc.y*h1 + wc.z*h2 + wc.w*xv);
    h0=h1; h1=h2; h2=xv;
    const floatx2* Bp2 = (const floatx2*)&sproj[tt*32];
    floatx2 zz = (floatx2)0.f;
#pragma unroll
    for (int k=0;k<8;k++) zz += Bp2[k]*w2[k];
    float z = fminf(zz.x + zz.y + bias, 60.f);
    const float E     = __expf(z);
    const float denom = 2.f + E;
    const float e     = __builtin_amdgcn_rcpf(denom);   // exp(-dt)
    const float dtv   = __logf(denom);                  // dt
    dt_s[tt]  = dtv;
    xcv_s[tt] = xcv;
    S += dtv;
    const floatx2 c2  = {dtv*xcv, dtv*xcv};
    const floatx2 es  = {e*e, e*e};
    floatx2 ep2 = {e, e*e};
#pragma unroll
    for (int k=0;k<8;k++){
      const floatx2 dA  = max2(ep2, eps2);
      const floatx2 dBx = max2(c2*Bp2[k], eps2);
      H2[k] = dA*H2[k] + dBx;
      ep2 *= es;
    }
  }
  Sarr[(size_t)(base+chunk)*2048 + d] = S;
  {
    float* o = Hc + (size_t)(base+chunk)*32768 + d;
#pragma unroll
    for (int k=0;k<8;k++){
      o[(size_t)(2*k  )*2048] = H2[k].x;
      o[(size_t)(2*k+1)*2048] = H2[k].y;
    }
  }

  gbar(bar+0, 896);

  // ---- phase 2: cross-chunk combine (98304 items over 229376 threads) ----
  {
    int id = blockIdx.x*256 + tid;
    if (id < 98304){
      int base2, C;
      if (id < 32768)      { base2=0;  C=64; }
      else if (id < 65536) { id-=32768; base2=64; C=32; }
      else                 { id-=65536; base2=96; C=16; }
      const int n = id >> 11, dd = id & 2047;
      const float fn = -(float)(n+1);
      const size_t off = (size_t)base2*32768 + id;
      const float* hc = Hc + off;
      float* hi = Hinit + off;
      const float* sp = Sarr + (size_t)base2*2048 + dd;
      float H = 0.f;
      for (int c=0;c<C;c++){
        hi[(size_t)c*32768] = H;
        const float e = __expf(fn * sp[(size_t)c*2048]);
        H = e*H + hc[(size_t)c*32768];
      }
    }
  }

  gbar(bar+1, 896);

  // ---- phase 3: rerun recurrence from Hinit using saved dt/xcv ----
  {
    const float* hi = Hinit + (size_t)(base+chunk)*32768 + d;
#pragma unroll
    for (int k=0;k<8;k++){
      H2[k].x = hi[(size_t)(2*k  )*2048];
      H2[k].y = hi[(size_t)(2*k+1)*2048];
    }
  }
  const float Dv = Dp_all[s*DIN + d];
  float* yp = y + (size_t)t0*DIN + d;
#pragma unroll
  for (int tt=0; tt<16; tt++){
    const float dtv = dt_s[tt];
    const float xcv = xcv_s[tt];
    const float e   = __expf(-dtv);
    const floatx2* Bp2 = (const floatx2*)&sproj[tt*32];
    const floatx2 c2 = {dtv*xcv, dtv*xcv};
    const floatx2 es = {e*e, e*e};
    floatx2 ep2 = {e, e*e};
    floatx2 pacc2 = (floatx2)0.f;
#pragma unroll
    for (int k=0;k<8;k++){
      const floatx2 dA  = max2(ep2, eps2);
      const floatx2 dBx = max2(c2*Bp2[k], eps2);
      H2[k] = dA*H2[k] + dBx;
      pacc2 += Bp2[8+k]*H2[k];
      ep2 *= es;
    }
    yp[(size_t)tt*DIN] = pacc2.x + pacc2.y + Dv*xcv;
  }

  gbar(bar+2, 896);

  // ---- phase 4: upsample + fuse + ctx (grid-stride over 1024x2048) ----
  {
    const float w0r = sw[0], w1r = sw[1], w2r = sw[2];
    const float mx = fmaxf(w0r, fmaxf(w1r, w2r));
    float e0 = __expf(w0r-mx), e1 = __expf(w1r-mx), e2 = __expf(w2r-mx);
    const float inv = 1.f/(e0+e1+e2);
    e0 *= inv; e1 *= inv; e2 *= inv;
    const int gid = blockIdx.x*256 + tid;
    for (int idx = gid; idx < 1024*2048; idx += 896*256){
      const int t = idx >> 11, dd = idx & 2047;
      const float o0 = y0[idx];
      const float o1 = ups_read(y1, 512, t, dd);
      const float o2 = ups_read(y2, 256, t, dd);
      fusedo[idx] = e0*o0 + e1*o1 + e2*o2;
      ctxb[idx]   = f2bf((o0+o1+o2)*(1.f/3.f));
    }
  }
}

// ---------------- LayerNorm (reads split-K partials + residual) ----------------
__global__ __launch_bounds__(256) void ln_kernel(const float* __restrict__ ya,
    const float* __restrict__ yb, const float* __restrict__ xr,
    const float* __restrict__ g, const float* __restrict__ b, float* __restrict__ out){
  __shared__ float red[4];
  const int t = blockIdx.x;
  const size_t ro = (size_t)t*1024;
  float v[4];
  float s = 0.f;
#pragma unroll
  for (int i=0;i<4;i++){
    const int c = threadIdx.x + i*256;
    v[i] = ya[ro+c] + yb[ro+c] + xr[ro+c];
    s += v[i];
  }
  s += __shfl_xor(s,1); s += __shfl_xor(s,2); s += __shfl_xor(s,4);
  s += __shfl_xor(s,8); s += __shfl_xor(s,16); s += __shfl_xor(s,32);
  if ((threadIdx.x & 63) == 0) red[threadIdx.x>>6] = s;
  __syncthreads();
  const float mu = (red[0]+red[1]+red[2]+red[3]) * (1.f/1024.f);
  __syncthreads();
  float q = 0.f;
#pragma unroll
  for (int i=0;i<4;i++){ const float dd = v[i]-mu; q += dd*dd; }
  q += __shfl_xor(q,1); q += __shfl_xor(q,2); q += __shfl_xor(q,4);
  q += __shfl_xor(q,8); q += __shfl_xor(q,16); q += __shfl_xor(q,32);
  if ((threadIdx.x & 63) == 0) red[threadIdx.x>>6] = q;
  __syncthreads();
  const float rstd = rsqrtf((red[0]+red[1]+red[2]+red[3]) * (1.f/1024.f) + 1e-5f);
#pragma unroll
  for (int i=0;i<4;i++){
    const int c = threadIdx.x + i*256;
    out[ro + c] = (v[i]-mu)*rstd*g[c] + b[c];
  }
}

extern "C" void kernel_launch(void* const* d_in, const int* in_sizes, int n_in,
                              void* d_out, int out_size, void* d_ws, size_t ws_size,
                              hipStream_t stream) {
  const float* x     = (const float*)d_in[0];
  const float* inpw  = (const float*)d_in[1];
  const float* convw = (const float*)d_in[2];
  const float* convb = (const float*)d_in[3];
  const float* xpw   = (const float*)d_in[4];
  const float* dtw   = (const float*)d_in[5];
  const float* dtb   = (const float*)d_in[6];
  const float* Dp    = (const float*)d_in[7];
  const float* sw    = (const float*)d_in[8];
  const float* gw1   = (const float*)d_in[9];
  const float* gw2   = (const float*)d_in[10];
  const float* opw   = (const float*)d_in[11];
  const float* lng   = (const float*)d_in[12];
  const float* lnb   = (const float*)d_in[13];
  float* out = (float*)d_out;

  char* ws = (char*)d_ws;
  u16*      wInp  = (u16*)     (ws + OFF_WINP);
  u16*      wG1   = (u16*)     (ws + OFF_WG1);
  u16*      wG2   = (u16*)     (ws + OFF_WG2);
  u16*      wOp   = (u16*)     (ws + OFF_WOP);
  u16*      xb    = (u16*)     (ws + OFF_XB);
  float*    xin   = (float*)   (ws + OFF_XIN);
  float*    sgate = (float*)   (ws + OFF_SGATE);
  float*    x1    = (float*)   (ws + OFF_X1);
  float*    x2    = (float*)   (ws + OFF_X2);
  float*    y0    = (float*)   (ws + OFF_Y0);
  float*    y1    = (float*)   (ws + OFF_Y1);
  float*    y2    = (float*)   (ws + OFF_Y2);
  float*    p0    = (float*)   (ws + OFF_P0);
  float*    p1    = (float*)   (ws + OFF_P1);
  float*    p2    = (float*)   (ws + OFF_P2);
  float*    Sarr  = (float*)   (ws + OFF_SARR);
  float*    Hc    = (float*)   (ws + OFF_HC);
  float*    Hinit = (float*)   (ws + OFF_HINIT);
  u16*      ctxb  = (u16*)     (ws + OFF_CTXB);
  u16*      t1b   = (u16*)     (ws + OFF_T1B);
  float*    fused = (float*)   (ws + OFF_FUSED);
  u16*      g3o   = (u16*)     (ws + OFF_G3O);
  float*    t1a0  = (float*)   (ws + OFF_T1A0);
  float*    t1a1  = (float*)   (ws + OFF_T1A1);
  float*    ypa0  = (float*)   (ws + OFF_YPA0);
  float*    ypa1  = (float*)   (ws + OFF_YPA1);
  unsigned* bar   = (unsigned*)(ws + OFF_BAR);

  // convert f32 -> bf16 (inpw + x) and zero the scan barrier counters (atomic stores)
  cvt_kernel<<<5120, 256, 0, stream>>>(inpw, wInp, x, xb, bar);
  // G1: xz = x @ in_proj_w^T -> x_in (f32) + downsampled x1,x2 + silu(gate)
  gemm_bt<0,64><<<dim3(64, 16, 1), 256, 0, stream>>>(xb, wInp, 4096, 1024, 1024,
                                                     xin, sgate, nullptr, nullptr, nullptr, x1, x2);
  // xproj (conv fused in-kernel) + piggybacked gate-weight bf16 conversion
  xproj_kernel<<<7936, 256, 0, stream>>>(xin, x1, x2, convw, convb, xpw, p0, p1, p2,
                                         gw1, wG1, gw2, wG2, opw, wOp);
  // fused scan: p1 + combine + p2 + fuse in ONE kernel (hardened grid barriers)
  scan_fused<<<896, 256, 0, stream>>>(xin, x1, x2, p0, p1, p2, convw, convb, dtw, dtb,
                                      Dp, sw, Sarr, Hc, Hinit, y0, y1, y2,
                                      ctxb, fused, bar);
  // G2: ctx @ gate_w1^T  split-K=2 -> partials  [512 blocks, 2/CU]
  gemm_bt<4,64><<<dim3(16, 16, 2), 256, 0, stream>>>(ctxb, wG1, 1024, 2048, 1024,
                                                     t1a0, t1a1, nullptr, nullptr, nullptr, nullptr, nullptr);
  g2_epi<<<1024, 256, 0, stream>>>(t1a0, t1a1, t1b);
  // G3: g3o = sigmoid(t1 @ gate_w2^T) * fused * sgate  [512 blocks]
  gemm_bt<2,64><<<dim3(32, 16, 1), 256, 0, stream>>>(t1b, wG2, 2048, 1024, 1024,
                                                     nullptr, nullptr, g3o, fused, sgate, nullptr, nullptr);
  // G4: g3o @ out_proj_w^T  split-K=2 -> partials  [512 blocks]
  gemm_bt<4,64><<<dim3(16, 16, 2), 256, 0, stream>>>(g3o, wOp, 1024, 2048, 1024,
                                                     ypa0, ypa1, nullptr, nullptr, nullptr, nullptr, nullptr);
  // LayerNorm (sums partials + residual) -> f32 out
  ln_kernel<<<1024, 256, 0, stream>>>(ypa0, ypa1, x, lng, lnb, out);
}

// Round 12
// 280.005 us; speedup vs baseline: 2.0219x; 2.0219x over previous
//
#include <hip/hip_runtime.h>

typedef unsigned short u16;
typedef float floatx2 __attribute__((ext_vector_type(2)));
typedef float floatx4 __attribute__((ext_vector_type(4)));
typedef short shortx8 __attribute__((ext_vector_type(8)));

#define DIN 2048

__device__ __forceinline__ u16 f2bf(float f){
  unsigned u = __float_as_uint(f);
  u = (u + 0x7fffu + ((u>>16)&1u))>>16;
  return (u16)u;
}
__device__ __forceinline__ float sigf(float x){ return 1.f/(1.f+__expf(-x)); }
__device__ __forceinline__ float siluf(float x){ return x*sigf(x); }
__device__ __forceinline__ floatx2 max2(floatx2 a, floatx2 b){
  floatx2 r; r.x = fmaxf(a.x, b.x); r.y = fmaxf(a.y, b.y); return r;
}

// ---------------- workspace layout (bytes) ----------------
#define OFF_WINP  0ull            // 4096x1024 bf16
#define OFF_WG1   8388608ull      // 1024x2048 bf16
#define OFF_WG2   12582912ull     // 2048x1024 bf16
#define OFF_WOP   16777216ull     // 1024x2048 bf16
#define OFF_XB    20971520ull     // 1024x1024 bf16
#define OFF_XIN   23068672ull     // 1024x2048 f32 (xin -> t1acc0)
#define OFF_SGATE 31457280ull     // 1024x2048 f32 silu(gate)
#define OFF_X1    39845888ull     // 512x2048 f32  (x1 -> t1acc1)
#define OFF_X2    44040192ull     // 256x2048 f32
#define OFF_XC0   46137344ull     // ctxb bf16 (first 4MB); +4MB -> ypa1
#define OFF_XC1   54525952ull     // t1b bf16
#define OFF_FUSED 60817408ull     // 1024x2048 f32 fused
#define OFF_G3O   69206016ull     // g3o bf16 4MB
#define OFF_Y0    75497472ull     // 1024x2048 f32
#define OFF_Y1    83886080ull     // 512x2048 f32  (-> ypa0)
#define OFF_Y2    88080384ull     // 256x2048 f32
#define OFF_P0    90177536ull     // 1024x32 f32
#define OFF_P1    90308608ull     // 512x32 f32
#define OFF_P2    90374144ull     // 256x32 f32
#define OFF_HC    92274688ull     // 112 x 32768 f32 = 14,680,064 B  (chunk-local H)
#define OFF_HINIT 121634816ull    // 112 x 32768 f32 = 14,680,064 B
#define OFF_SARR  136314880ull    // 112 x 2048 f32  = 917,504 B
// aliases
#define OFF_CTXB  OFF_XC0
#define OFF_T1B   OFF_XC1
#define OFF_T1A0  OFF_XIN
#define OFF_T1A1  OFF_X1
#define OFF_YPA0  OFF_Y1
#define OFF_YPA1  (OFF_XC0 + 4194304ull)

__device__ __forceinline__ void gld_lds16(const void* g, void* l){
  __builtin_amdgcn_global_load_lds((const __attribute__((address_space(1))) unsigned*)g,
                                   (__attribute__((address_space(3))) unsigned*)l, 16, 0, 0);
}

// ---------------- f32 -> bf16 conversion (inpw + x; gate weights ride xproj) -------
__global__ __launch_bounds__(256) void cvt_kernel(
    const float* __restrict__ s0, u16* __restrict__ d0,
    const float* __restrict__ s1, u16* __restrict__ d1)
{
  int i = (blockIdx.x*256 + threadIdx.x)*4;
  const float* s; u16* d;
  if (i < 4194304){ s=s0; d=d0; }
  else            { s=s1; d=d1; i -= 4194304; }
  const float4 v = *(const float4*)(s + i);
  ushort4 o; o.x = f2bf(v.x); o.y = f2bf(v.y); o.z = f2bf(v.z); o.w = f2bf(v.w);
  *(ushort4*)(d + i) = o;
}

// ---------------- MFMA bt-GEMM (R1/R3-proven): BK=32, dbuf ----------
// MODE 0: G1 epilogue (xin + downsamples | silu->sgate)
// MODE 2: G3 epilogue (sigmoid * fused * sgate -> bf16)
// MODE 4: plain f32 (split-K aware via blockIdx.z)
template<int MODE, int BM>
__global__ __launch_bounds__(256) void gemm_bt(
    const u16* __restrict__ A, const u16* __restrict__ B,
    int N, int K, int Ks,
    float* __restrict__ out_f, float* __restrict__ out_f2, u16* __restrict__ out_b,
    const float* __restrict__ ex0f, const float* __restrict__ ex1f,
    float* __restrict__ ex0, float* __restrict__ ex1)
{
  constexpr int NI = BM/32;
  constexpr int IP = BM/64;
  __shared__ u16 smA[2][BM*32];
  __shared__ u16 smB[2][BM*32];
  const int tid  = threadIdx.x;
  const int m0   = blockIdx.y * BM;
  const int n0   = blockIdx.x * BM;
  const int wv   = tid >> 6;
  const int lane = tid & 63;
  const int mw   = (wv >> 1) * (BM/2);
  const int nw   = (wv & 1) * (BM/2);
  const int quad = lane >> 4;
  const int l16  = lane & 15;
  const int srow = tid >> 2;
  const int scol = (tid & 3) * 8;

  floatx4 acc[NI][NI];
#pragma unroll
  for (int i=0;i<NI;i++)
#pragma unroll
    for (int j=0;j<NI;j++) acc[i][j] = (floatx4)0.f;

  const int kStart = blockIdx.z * Ks;
  const int kEnd   = kStart + Ks;

  auto stage = [&](int buf, int k0){
#pragma unroll
    for (int p=0;p<IP;p++){
      gld_lds16(A + (size_t)(m0 + p*64 + srow)*K + k0 + scol, &smA[buf][p*2048 + wv*512]);
      gld_lds16(B + (size_t)(n0 + p*64 + srow)*K + k0 + scol, &smB[buf][p*2048 + wv*512]);
    }
  };

  stage(0, kStart);
  int cur = 0;
  for (int k0 = kStart; k0 < kEnd; k0 += 32) {
    __syncthreads();
    if (k0 + 32 < kEnd) stage(cur^1, k0+32);
    shortx8 af[NI], bfr[NI];
#pragma unroll
    for (int i=0;i<NI;i++){
      af[i]  = *(const shortx8*)&smA[cur][(mw + i*16 + l16)*32 + quad*8];
      bfr[i] = *(const shortx8*)&smB[cur][(nw + i*16 + l16)*32 + quad*8];
    }
#pragma unroll
    for (int i=0;i<NI;i++)
#pragma unroll
      for (int j=0;j<NI;j++)
        acc[i][j] = __builtin_amdgcn_mfma_f32_16x16x32_bf16(af[i], bfr[j], acc[i][j], 0, 0, 0);
    cur ^= 1;
  }

#pragma unroll
  for (int i=0;i<NI;i++){
    const int mb = m0 + mw + i*16 + quad*4;
#pragma unroll
    for (int j=0;j<NI;j++){
      const int n = n0 + nw + j*16 + l16;
      const floatx4 v4 = acc[i][j];
      if (MODE == 0){
        if (n < 2048){
#pragma unroll
          for (int r=0;r<4;r++) out_f[(size_t)(mb+r)*2048 + n] = v4[r];
          ex0[(size_t)(mb>>1)*2048 + n]       = 0.5f*(v4[0]+v4[1]);
          ex0[(size_t)((mb>>1)+1)*2048 + n]   = 0.5f*(v4[2]+v4[3]);
          ex1[(size_t)(mb>>2)*2048 + n]       = 0.25f*(v4[0]+v4[1]+v4[2]+v4[3]);
        } else {
#pragma unroll
          for (int r=0;r<4;r++) out_f2[(size_t)(mb+r)*2048 + (n-2048)] = siluf(v4[r]);
        }
      } else if (MODE == 2){
#pragma unroll
        for (int r=0;r<4;r++){
          const size_t idx = (size_t)(mb+r)*N + n;
          out_b[idx] = f2bf(sigf(v4[r]) * ex0f[idx] * ex1f[idx]);
        }
      } else {
        float* dst = blockIdx.z ? out_f2 : out_f;
#pragma unroll
        for (int r=0;r<4;r++) dst[(size_t)(mb+r)*N + n] = v4[r];
      }
    }
  }
}

// ---------------- G2 combine: t1 = silu(acc0+acc1) -> bf16 ----------------
__global__ __launch_bounds__(256) void g2_epi(const float* __restrict__ a,
    const float* __restrict__ b, u16* __restrict__ o){
  const int i = (blockIdx.x*256 + threadIdx.x)*4;
  const float4 va = *(const float4*)(a+i);
  const float4 vb = *(const float4*)(b+i);
  ushort4 r;
  r.x = f2bf(siluf(va.x+vb.x)); r.y = f2bf(siluf(va.y+vb.y));
  r.z = f2bf(siluf(va.z+vb.z)); r.w = f2bf(siluf(va.w+vb.w));
  *(ushort4*)(o+i) = r;
}

// ---------------- xproj with inline conv + piggybacked gate-weight cvt ----------
// blocks [0,1792): xproj.  blocks [1792, 7936): stream-convert gw1/gw2/opw -> bf16.
__global__ __launch_bounds__(256) void xproj_kernel(const float* __restrict__ x0,
    const float* __restrict__ x1, const float* __restrict__ x2,
    const float* __restrict__ cw, const float* __restrict__ cb,
    const float* __restrict__ xw,
    float* __restrict__ p0, float* __restrict__ p1, float* __restrict__ p2,
    const float* __restrict__ gw1c, u16* __restrict__ wG1o,
    const float* __restrict__ gw2c, u16* __restrict__ wG2o,
    const float* __restrict__ opwc, u16* __restrict__ wOpo){
  __shared__ float srow[DIN];
  if (blockIdx.x >= 1792){
    int i = (int)(blockIdx.x - 1792)*1024 + threadIdx.x*4;
    const float* sp; u16* dp;
    if (i < 2097152)      { sp=gw1c; dp=wG1o; }
    else if (i < 4194304) { sp=gw2c; dp=wG2o; i-=2097152; }
    else                  { sp=opwc; dp=wOpo; i-=4194304; }
    const float4 v = *(const float4*)(sp + i);
    ushort4 o; o.x = f2bf(v.x); o.y = f2bf(v.y); o.z = f2bf(v.z); o.w = f2bf(v.w);
    *(ushort4*)(dp + i) = o;
    return;
  }
  const int b = blockIdx.x;
  const float* xs; float* proj; int s, t;
  if (b < 1024)      { s=0; t=b;       xs=x0; proj=p0; }
  else if (b < 1536) { s=1; t=b-1024;  xs=x1; proj=p1; }
  else               { s=2; t=b-1536;  xs=x2; proj=p2; }
  const int tid = threadIdx.x;
#pragma unroll
  for (int q=0;q<2;q++){
    const int k = (q*256 + tid)*4;
    float4 xv[4];
#pragma unroll
    for (int j=0;j<4;j++){
      const int tt = t - 3 + j;
      if (tt >= 0) xv[j] = *(const float4*)(xs + (size_t)tt*DIN + k);
      else { xv[j].x = 0.f; xv[j].y = 0.f; xv[j].z = 0.f; xv[j].w = 0.f; }
    }
    const float4 w0 = *(const float4*)(cw + ((size_t)(s*DIN) + k + 0)*4);
    const float4 w1 = *(const float4*)(cw + ((size_t)(s*DIN) + k + 1)*4);
    const float4 w2 = *(const float4*)(cw + ((size_t)(s*DIN) + k + 2)*4);
    const float4 w3 = *(const float4*)(cw + ((size_t)(s*DIN) + k + 3)*4);
    const float4 cb4 = *(const float4*)(cb + (size_t)(s*DIN) + k);
    float4 r;
    r.x = siluf(cb4.x + w0.x*xv[0].x + w0.y*xv[1].x + w0.z*xv[2].x + w0.w*xv[3].x);
    r.y = siluf(cb4.y + w1.x*xv[0].y + w1.y*xv[1].y + w1.z*xv[2].y + w1.w*xv[3].y);
    r.z = siluf(cb4.z + w2.x*xv[0].z + w2.y*xv[1].z + w2.z*xv[2].z + w2.w*xv[3].z);
    r.w = siluf(cb4.w + w3.x*xv[0].w + w3.y*xv[1].w + w3.z*xv[2].w + w3.w*xv[3].w);
    *(float4*)&srow[k] = r;
  }
  __syncthreads();
  const int i = tid >> 3;
  const int j = tid & 7;
  const float4* w4 = (const float4*)(xw + ((size_t)s*32 + i)*DIN);
  const float4* s4 = (const float4*)srow;
  float acc = 0.f;
#pragma unroll 8
  for (int c=0;c<64;c++){
    const float4 sv = s4[j + 8*c];
    const float4 wv = w4[j + 8*c];
    acc += sv.x*wv.x + sv.y*wv.y + sv.z*wv.z + sv.w*wv.w;
  }
  acc += __shfl_xor(acc,1); acc += __shfl_xor(acc,2); acc += __shfl_xor(acc,4);
  if (j == 0) proj[t*32 + i] = acc;
}

// ---------------- chunked scan, phase 1: L=16, conv fused, S + H split ----------
// dt = softplus(softplus(z)) = log(2+e^z);  exp(-dt) = 1/(2+e^z).
__global__ __launch_bounds__(128) void scan_p1(
    const float* __restrict__ x0, const float* __restrict__ x1, const float* __restrict__ x2,
    const float* __restrict__ p0, const float* __restrict__ p1, const float* __restrict__ p2,
    const float* __restrict__ cw, const float* __restrict__ cb,
    const float* __restrict__ dtw, const float* __restrict__ dtb,
    float* __restrict__ Sarr, float* __restrict__ Hc)
{
  __shared__ float sproj[16*32];
  int b = blockIdx.x;
  const float *xs, *proj; int base, s;
  if (b < 1024)      { xs=x0; proj=p0; base=0;  s=0; }
  else if (b < 1536) { b-=1024; xs=x1; proj=p1; base=64; s=1; }
  else               { b-=1536; xs=x2; proj=p2; base=96; s=2; }
  const int chunk = b >> 4;
  const int tid   = threadIdx.x;
  const int d     = (b & 15)*128 + tid;
  const int t0    = chunk*16;
  {
    const int k = tid*4;
    *(float4*)&sproj[k] = *(const float4*)&proj[t0*32 + k];
  }
  __syncthreads();

  const float4 wc  = *(const float4*)(cw + ((size_t)(s*DIN) + d)*4);
  const float  cbv = cb[s*DIN + d];
  floatx2 w2[8];
  const floatx2* wr = (const floatx2*)(dtw + ((size_t)(s*DIN) + d)*16);
#pragma unroll
  for (int k=0;k<8;k++) w2[k] = wr[k];
  const float bias = dtb[s*DIN + d];
  const floatx2 eps2 = {1e-38f, 1e-38f};

  floatx2 H2[8];
#pragma unroll
  for (int k=0;k<8;k++) H2[k] = (floatx2)0.f;
  float S = 0.f;
  const float* xp = xs + d;
  float h0=0.f, h1=0.f, h2=0.f;
  if (chunk){
    h0 = xp[(size_t)(t0-3)*DIN];
    h1 = xp[(size_t)(t0-2)*DIN];
    h2 = xp[(size_t)(t0-1)*DIN];
  }
  for (int tt=0; tt<16; tt++){
    const float xv  = xp[(size_t)(t0+tt)*DIN];
    const float xcv = siluf(cbv + wc.x*h0 + wc.y*h1 + wc.z*h2 + wc.w*xv);
    h0=h1; h1=h2; h2=xv;
    const floatx2* Bp2 = (const floatx2*)&sproj[tt*32];
    floatx2 zz = (floatx2)0.f;
#pragma unroll
    for (int k=0;k<8;k++) zz += Bp2[k]*w2[k];
    float z = fminf(zz.x + zz.y + bias, 60.f);
    const float E     = __expf(z);
    const float denom = 2.f + E;
    const float e     = __builtin_amdgcn_rcpf(denom);   // exp(-dt)
    const float dtv   = __logf(denom);                  // dt
    S += dtv;
    const floatx2 c2  = {dtv*xcv, dtv*xcv};
    const floatx2 es  = {e*e, e*e};
    floatx2 ep2 = {e, e*e};
#pragma unroll
    for (int k=0;k<8;k++){
      const floatx2 dA  = max2(ep2, eps2);
      const floatx2 dBx = max2(c2*Bp2[k], eps2);
      H2[k] = dA*H2[k] + dBx;
      ep2 *= es;
    }
  }
  Sarr[(size_t)(base+chunk)*2048 + d] = S;
  float* o = Hc + (size_t)(base+chunk)*32768 + d;
#pragma unroll
  for (int k=0;k<8;k++){
    o[(size_t)(2*k  )*2048] = H2[k].x;
    o[(size_t)(2*k+1)*2048] = H2[k].y;
  }
}

// ---------------- combine (112 chunk rows; C=64/32/16); P[n]=exp(-(n+1)S) --------
__global__ __launch_bounds__(256) void scan_combine(const float* __restrict__ Sarr,
    const float* __restrict__ Hc, float* __restrict__ Hinit){
  int id = blockIdx.x*256 + threadIdx.x;
  int base, C;
  if (id < 32768)      { base=0;  C=64; }
  else if (id < 65536) { id-=32768; base=64; C=32; }
  else                 { id-=65536; base=96; C=16; }
  const int n = id >> 11, d = id & 2047;
  const float fn = -(float)(n+1);
  const size_t off = (size_t)base*32768 + id;
  const float* hc = Hc + off;
  float* hi = Hinit + off;
  const float* sp = Sarr + (size_t)base*2048 + d;
  float H = 0.f;
  for (int c=0;c<C;c++){
    hi[(size_t)c*32768] = H;
    const float e = __expf(fn * sp[(size_t)c*2048]);
    H = e*H + hc[(size_t)c*32768];
  }
}

// ---------------- chunked scan, phase 2: conv + dt recomputed, state-major Hinit ---
__global__ __launch_bounds__(128) void scan_p2(
    const float* __restrict__ x0, const float* __restrict__ x1, const float* __restrict__ x2,
    const float* __restrict__ p0, const float* __restrict__ p1, const float* __restrict__ p2,
    const float* __restrict__ cw, const float* __restrict__ cb,
    const float* __restrict__ dtw, const float* __restrict__ dtb,
    const float* __restrict__ Hinit, const float* __restrict__ Dp_all,
    float* __restrict__ y0, float* __restrict__ y1, float* __restrict__ y2)
{
  __shared__ float sproj[16*32];
  int b = blockIdx.x;
  const float *xs, *proj; float* y; int base, s;
  if (b < 1024)      { xs=x0; proj=p0; y=y0; base=0;  s=0; }
  else if (b < 1536) { b-=1024; xs=x1; proj=p1; y=y1; base=64; s=1; }
  else               { b-=1536; xs=x2; proj=p2; y=y2; base=96; s=2; }
  const int chunk = b >> 4;
  const int tid   = threadIdx.x;
  const int d     = (b & 15)*128 + tid;
  const int t0    = chunk*16;
  {
    const int k = tid*4;
    *(float4*)&sproj[k] = *(const float4*)&proj[t0*32 + k];
  }
  __syncthreads();

  const float4 wc  = *(const float4*)(cw + ((size_t)(s*DIN) + d)*4);
  const float  cbv = cb[s*DIN + d];
  floatx2 w2[8];
  const floatx2* wr = (const floatx2*)(dtw + ((size_t)(s*DIN) + d)*16);
#pragma unroll
  for (int k=0;k<8;k++) w2[k] = wr[k];
  const float bias = dtb[s*DIN + d];

  floatx2 H2[8];
  const float* hi = Hinit + (size_t)(base+chunk)*32768 + d;
#pragma unroll
  for (int k=0;k<8;k++){
    H2[k].x = hi[(size_t)(2*k  )*2048];
    H2[k].y = hi[(size_t)(2*k+1)*2048];
  }
  const float Dv = Dp_all[s*DIN + d];
  const floatx2 eps2 = {1e-38f, 1e-38f};
  const float* xp = xs + d;
  float* yp = y + (size_t)t0*DIN + d;
  float h0=0.f, h1=0.f, h2=0.f;
  if (chunk){
    h0 = xp[(size_t)(t0-3)*DIN];
    h1 = xp[(size_t)(t0-2)*DIN];
    h2 = xp[(size_t)(t0-1)*DIN];
  }
  for (int tt=0; tt<16; tt++){
    const float xv  = xp[(size_t)(t0+tt)*DIN];
    const float xcv = siluf(cbv + wc.x*h0 + wc.y*h1 + wc.z*h2 + wc.w*xv);
    h0=h1; h1=h2; h2=xv;
    const floatx2* Bp2 = (const floatx2*)&sproj[tt*32];
    floatx2 zz = (floatx2)0.f;
#pragma unroll
    for (int k=0;k<8;k++) zz += Bp2[k]*w2[k];
    float z = fminf(zz.x + zz.y + bias, 60.f);
    const float E     = __expf(z);
    const float denom = 2.f + E;
    const float e     = __builtin_amdgcn_rcpf(denom);   // exp(-dt)
    const float dtv   = __logf(denom);                  // dt
    const floatx2 c2 = {dtv*xcv, dtv*xcv};
    const floatx2 es = {e*e, e*e};
    floatx2 ep2 = {e, e*e};
    floatx2 pacc2 = (floatx2)0.f;
#pragma unroll
    for (int k=0;k<8;k++){
      const floatx2 dA  = max2(ep2, eps2);
      const floatx2 dBx = max2(c2*Bp2[k], eps2);
      H2[k] = dA*H2[k] + dBx;
      pacc2 += Bp2[8+k]*H2[k];
      ep2 *= es;
    }
    yp[(size_t)tt*DIN] = pacc2.x + pacc2.y + Dv*xcv;
  }
}

// ---------------- upsample + fuse + ctx ----------------
__device__ __forceinline__ float ups_read(const float* __restrict__ ys, int Tin, int t, int d){
  const float scale = (float)Tin * (1.f/1024.f);
  float pos = ((float)t + 0.5f)*scale - 0.5f;
  pos = fminf(fmaxf(pos, 0.f), (float)(Tin-1));
  const int lo = (int)floorf(pos);
  const float w = pos - (float)lo;
  const int hi = min(lo+1, Tin-1);
  return ys[(size_t)lo*DIN + d]*(1.f-w) + ys[(size_t)hi*DIN + d]*w;
}

__global__ __launch_bounds__(256) void fuse_kernel(const float* __restrict__ y0,
    const float* __restrict__ y1, const float* __restrict__ y2,
    const float* __restrict__ sw, u16* __restrict__ ctxb, float* __restrict__ fused){
  const int idx = blockIdx.x*256 + threadIdx.x;
  const int t = idx >> 11, d = idx & 2047;
  const float w0r = sw[0], w1r = sw[1], w2r = sw[2];
  const float mx = fmaxf(w0r, fmaxf(w1r, w2r));
  float e0 = __expf(w0r-mx), e1 = __expf(w1r-mx), e2 = __expf(w2r-mx);
  const float inv = 1.f/(e0+e1+e2);
  e0 *= inv; e1 *= inv; e2 *= inv;
  const float o0 = y0[idx];
  const float o1 = ups_read(y1, 512, t, d);
  const float o2 = ups_read(y2, 256, t, d);
  fused[idx] = e0*o0 + e1*o1 + e2*o2;
  ctxb[idx]  = f2bf((o0+o1+o2)*(1.f/3.f));
}

// ---------------- LayerNorm (reads split-K partials + residual) ----------------
__global__ __launch_bounds__(256) void ln_kernel(const float* __restrict__ ya,
    const float* __restrict__ yb, const float* __restrict__ xr,
    const float* __restrict__ g, const float* __restrict__ b, float* __restrict__ out){
  __shared__ float red[4];
  const int t = blockIdx.x;
  const size_t ro = (size_t)t*1024;
  float v[4];
  float s = 0.f;
#pragma unroll
  for (int i=0;i<4;i++){
    const int c = threadIdx.x + i*256;
    v[i] = ya[ro+c] + yb[ro+c] + xr[ro+c];
    s += v[i];
  }
  s += __shfl_xor(s,1); s += __shfl_xor(s,2); s += __shfl_xor(s,4);
  s += __shfl_xor(s,8); s += __shfl_xor(s,16); s += __shfl_xor(s,32);
  if ((threadIdx.x & 63) == 0) red[threadIdx.x>>6] = s;
  __syncthreads();
  const float mu = (red[0]+red[1]+red[2]+red[3]) * (1.f/1024.f);
  __syncthreads();
  float q = 0.f;
#pragma unroll
  for (int i=0;i<4;i++){ const float dd = v[i]-mu; q += dd*dd; }
  q += __shfl_xor(q,1); q += __shfl_xor(q,2); q += __shfl_xor(q,4);
  q += __shfl_xor(q,8); q += __shfl_xor(q,16); q += __shfl_xor(q,32);
  if ((threadIdx.x & 63) == 0) red[threadIdx.x>>6] = q;
  __syncthreads();
  const float rstd = rsqrtf((red[0]+red[1]+red[2]+red[3]) * (1.f/1024.f) + 1e-5f);
#pragma unroll
  for (int i=0;i<4;i++){
    const int c = threadIdx.x + i*256;
    out[ro + c] = (v[i]-mu)*rstd*g[c] + b[c];
  }
}

extern "C" void kernel_launch(void* const* d_in, const int* in_sizes, int n_in,
                              void* d_out, int out_size, void* d_ws, size_t ws_size,
                              hipStream_t stream) {
  const float* x     = (const float*)d_in[0];
  const float* inpw  = (const float*)d_in[1];
  const float* convw = (const float*)d_in[2];
  const float* convb = (const float*)d_in[3];
  const float* xpw   = (const float*)d_in[4];
  const float* dtw   = (const float*)d_in[5];
  const float* dtb   = (const float*)d_in[6];
  const float* Dp    = (const float*)d_in[7];
  const float* sw    = (const float*)d_in[8];
  const float* gw1   = (const float*)d_in[9];
  const float* gw2   = (const float*)d_in[10];
  const float* opw   = (const float*)d_in[11];
  const float* lng   = (const float*)d_in[12];
  const float* lnb   = (const float*)d_in[13];
  float* out = (float*)d_out;

  char* ws = (char*)d_ws;
  u16*    wInp  = (u16*)   (ws + OFF_WINP);
  u16*    wG1   = (u16*)   (ws + OFF_WG1);
  u16*    wG2   = (u16*)   (ws + OFF_WG2);
  u16*    wOp   = (u16*)   (ws + OFF_WOP);
  u16*    xb    = (u16*)   (ws + OFF_XB);
  float*  xin   = (float*) (ws + OFF_XIN);
  float*  sgate = (float*) (ws + OFF_SGATE);
  float*  x1    = (float*) (ws + OFF_X1);
  float*  x2    = (float*) (ws + OFF_X2);
  float*  y0    = (float*) (ws + OFF_Y0);
  float*  y1    = (float*) (ws + OFF_Y1);
  float*  y2    = (float*) (ws + OFF_Y2);
  float*  p0    = (float*) (ws + OFF_P0);
  float*  p1    = (float*) (ws + OFF_P1);
  float*  p2    = (float*) (ws + OFF_P2);
  float*  Sarr  = (float*) (ws + OFF_SARR);
  float*  Hc    = (float*) (ws + OFF_HC);
  float*  Hinit = (float*) (ws + OFF_HINIT);
  u16*    ctxb  = (u16*)   (ws + OFF_CTXB);
  u16*    t1b   = (u16*)   (ws + OFF_T1B);
  float*  fused = (float*) (ws + OFF_FUSED);
  u16*    g3o   = (u16*)   (ws + OFF_G3O);
  float*  t1a0  = (float*) (ws + OFF_T1A0);
  float*  t1a1  = (float*) (ws + OFF_T1A1);
  float*  ypa0  = (float*) (ws + OFF_YPA0);
  float*  ypa1  = (float*) (ws + OFF_YPA1);

  // convert f32 -> bf16: in_proj weights + x (gate weights ride the xproj dispatch)
  cvt_kernel<<<5120, 256, 0, stream>>>(inpw, wInp, x, xb);
  // G1: xz = x @ in_proj_w^T -> x_in (f32) + downsampled x1,x2 + silu(gate)
  gemm_bt<0,64><<<dim3(64, 16, 1), 256, 0, stream>>>(xb, wInp, 4096, 1024, 1024,
                                                     xin, sgate, nullptr, nullptr, nullptr, x1, x2);
  // xproj (conv fused in-kernel) + piggybacked gate-weight bf16 conversion
  xproj_kernel<<<7936, 256, 0, stream>>>(xin, x1, x2, convw, convb, xpw, p0, p1, p2,
                                         gw1, wG1, gw2, wG2, opw, wOp);
  // chunked SSM scan (L=16; conv + dt recomputed inline; S/H split, state-major)
  scan_p1<<<1792, 128, 0, stream>>>(xin, x1, x2, p0, p1, p2, convw, convb, dtw, dtb, Sarr, Hc);
  scan_combine<<<384, 256, 0, stream>>>(Sarr, Hc, Hinit);
  scan_p2<<<1792, 128, 0, stream>>>(xin, x1, x2, p0, p1, p2, convw, convb, dtw, dtb,
                                    Hinit, Dp, y0, y1, y2);
  // upsample + fuse + ctx
  fuse_kernel<<<(1024*DIN)/256, 256, 0, stream>>>(y0, y1, y2, sw, ctxb, fused);
  // G2: ctx @ gate_w1^T  split-K=2 -> partials  [512 blocks, 2/CU]
  gemm_bt<4,64><<<dim3(16, 16, 2), 256, 0, stream>>>(ctxb, wG1, 1024, 2048, 1024,
                                                     t1a0, t1a1, nullptr, nullptr, nullptr, nullptr, nullptr);
  g2_epi<<<1024, 256, 0, stream>>>(t1a0, t1a1, t1b);
  // G3: g3o = sigmoid(t1 @ gate_w2^T) * fused * sgate  [512 blocks]
  gemm_bt<2,64><<<dim3(32, 16, 1), 256, 0, stream>>>(t1b, wG2, 2048, 1024, 1024,
                                                     nullptr, nullptr, g3o, fused, sgate, nullptr, nullptr);
  // G4: g3o @ out_proj_w^T  split-K=2 -> partials  [512 blocks]
  gemm_bt<4,64><<<dim3(16, 16, 2), 256, 0, stream>>>(g3o, wOp, 1024, 2048, 1024,
                                                     ypa0, ypa1, nullptr, nullptr, nullptr, nullptr, nullptr);
  // LayerNorm (sums partials + residual) -> f32 out
  ln_kernel<<<1024, 256, 0, stream>>>(ypa0, ypa1, x, lng, lnb, out);
}